// Round 7
// baseline (582.566 us; speedup 1.0000x reference)
//
#include <hip/hip_runtime.h>
#include <hip/hip_bf16.h>
#include <math.h>

typedef __attribute__((ext_vector_type(8))) short short8;
typedef __attribute__((ext_vector_type(4))) short short4v;
typedef __attribute__((ext_vector_type(4))) float floatx4;

#define D_MODEL 1024
#define N_HEADS 16
#define HEAD_DIM 64
#define D_FF 4096
#define BATCH 4
#define SEQ 2048
#define NTOK (BATCH * SEQ)  /* 8192 */

#define GLOBAL_AS __attribute__((address_space(1)))
#define LDS_AS __attribute__((address_space(3)))

// async global->LDS, 16B per lane; lds dst must be wave-uniform base (+lane*16 implicit)
__device__ __forceinline__ void async_ld16(const void* g, void* l) {
    __builtin_amdgcn_global_load_lds((GLOBAL_AS const unsigned int*)g,
                                     (LDS_AS unsigned int*)l, 16, 0, 0);
}

__device__ __forceinline__ short bf16s(float v) {
    __hip_bfloat16 h = __float2bfloat16(v);
    return *(short*)&h;
}

// packed f32x2 -> bf16x2 (v_cvt_pk_bf16_f32)
__device__ __forceinline__ unsigned int pk_bf16(float a, float b) {
    __hip_bfloat162 h = __float22bfloat162_rn(float2{a, b});
    return *(unsigned int*)&h;
}

// branch-free tanh-form GELU: ge = v - v/(exp2(v*(c2 + c2b*v^2)) + 1)
// c2 = 2*log2e*0.7978845608, c2b = c2*0.044715. |err vs exact erf-GELU| <= ~3e-3.
__device__ __forceinline__ float fast_gelu(float v) {
    const float t = exp2f(v * (2.302183f + 0.102953f * v * v));
    return v - v * __builtin_amdgcn_rcpf(t + 1.0f);
}

// ---------------- fused prep: 6 weight transposes + bias concat ----------------
// fp32 [R][C] -> bf16 [C][R]; block ranges select the matrix. grid: 12300 x 256.
__global__ void prep_kernel(const float* __restrict__ wq, const float* __restrict__ wk,
                            const float* __restrict__ wv, const float* __restrict__ wo,
                            const float* __restrict__ w1, const float* __restrict__ w2,
                            const float* __restrict__ bq, const float* __restrict__ bk,
                            const float* __restrict__ bv,
                            __hip_bfloat16* __restrict__ wqkvT, __hip_bfloat16* __restrict__ woT,
                            __hip_bfloat16* __restrict__ w1T, __hip_bfloat16* __restrict__ w2T,
                            float* __restrict__ bqkv) {
    const int id = blockIdx.x;
    if (id >= 12288) {  // bias concat: 12 blocks x 256 = 3072
        const int i = (id - 12288) * 256 + threadIdx.x;
        bqkv[i] = (i < 1024) ? bq[i] : (i < 2048 ? bk[i - 1024] : bv[i - 2048]);
        return;
    }
    const float* in;
    __hip_bfloat16* out;
    int R, C, t;
    if (id < 1024)      { in = wq; out = wqkvT;                          R = 1024; C = 1024; t = id; }
    else if (id < 2048) { in = wk; out = wqkvT + (size_t)1024 * 1024;    R = 1024; C = 1024; t = id - 1024; }
    else if (id < 3072) { in = wv; out = wqkvT + (size_t)2048 * 1024;    R = 1024; C = 1024; t = id - 2048; }
    else if (id < 4096) { in = wo; out = woT;                            R = 1024; C = 1024; t = id - 3072; }
    else if (id < 8192) { in = w1; out = w1T;                            R = 1024; C = 4096; t = id - 4096; }
    else                { in = w2; out = w2T;                            R = 4096; C = 1024; t = id - 8192; }
    const int cb = C >> 5;
    const int c0 = (t % cb) * 32, r0 = (t / cb) * 32;

    __shared__ float tile[32][33];
    const int tx = threadIdx.x & 31, ty = threadIdx.x >> 5;  // ty 0..7
#pragma unroll
    for (int i = 0; i < 4; ++i) {
        int r = ty + i * 8;
        tile[r][tx] = in[(size_t)(r0 + r) * C + c0 + tx];
    }
    __syncthreads();
#pragma unroll
    for (int i = 0; i < 4; ++i) {
        int r = ty + i * 8;  // output row = c0+r, col = r0+tx
        out[(size_t)(c0 + r) * R + r0 + tx] = __float2bfloat16(tile[tx][r]);
    }
}

// ---------------- LayerNorm: fp32 in -> bf16 out ----------------
__global__ void ln_kernel(const float* __restrict__ x, const float* __restrict__ g,
                          const float* __restrict__ b, __hip_bfloat16* __restrict__ out) {
    const int row = blockIdx.x;
    const int tid = threadIdx.x;
    const float4 v = ((const float4*)(x + (size_t)row * D_MODEL))[tid];
    float s = v.x + v.y + v.z + v.w;
    float s2 = v.x * v.x + v.y * v.y + v.z * v.z + v.w * v.w;
#pragma unroll
    for (int off = 32; off >= 1; off >>= 1) {
        s += __shfl_xor(s, off, 64);
        s2 += __shfl_xor(s2, off, 64);
    }
    __shared__ float ss[4], ss2[4];
    const int wid = tid >> 6, lane = tid & 63;
    if (lane == 0) { ss[wid] = s; ss2[wid] = s2; }
    __syncthreads();
    const float tot = ss[0] + ss[1] + ss[2] + ss[3];
    const float tot2 = ss2[0] + ss2[1] + ss2[2] + ss2[3];
    const float mu = tot * (1.0f / D_MODEL);
    const float var = tot2 * (1.0f / D_MODEL) - mu * mu;
    const float rsq = rsqrtf(var + 1e-5f);
    const float vv[4] = {v.x, v.y, v.z, v.w};
#pragma unroll
    for (int j = 0; j < 4; ++j) {
        int c = tid * 4 + j;
        out[(size_t)row * D_MODEL + c] = __float2bfloat16((vv[j] - mu) * rsq * g[c] + b[c]);
    }
}

// ---------------- LayerNorm: bf16 in -> bf16 out ----------------
__global__ void ln_bf16_kernel(const __hip_bfloat16* __restrict__ x, const float* __restrict__ g,
                               const float* __restrict__ b, __hip_bfloat16* __restrict__ out) {
    const int row = blockIdx.x;
    const int tid = threadIdx.x;
    const short4v raw = ((const short4v*)(x + (size_t)row * D_MODEL))[tid];
    float vv[4];
#pragma unroll
    for (int j = 0; j < 4; ++j) { short t = raw[j]; vv[j] = __bfloat162float(*(__hip_bfloat16*)&t); }
    float s = vv[0] + vv[1] + vv[2] + vv[3];
    float s2 = vv[0] * vv[0] + vv[1] * vv[1] + vv[2] * vv[2] + vv[3] * vv[3];
#pragma unroll
    for (int off = 32; off >= 1; off >>= 1) {
        s += __shfl_xor(s, off, 64);
        s2 += __shfl_xor(s2, off, 64);
    }
    __shared__ float ss[4], ss2[4];
    const int wid = tid >> 6, lane = tid & 63;
    if (lane == 0) { ss[wid] = s; ss2[wid] = s2; }
    __syncthreads();
    const float tot = ss[0] + ss[1] + ss[2] + ss[3];
    const float tot2 = ss2[0] + ss2[1] + ss2[2] + ss2[3];
    const float mu = tot * (1.0f / D_MODEL);
    const float var = tot2 * (1.0f / D_MODEL) - mu * mu;
    const float rsq = rsqrtf(var + 1e-5f);
#pragma unroll
    for (int j = 0; j < 4; ++j) {
        int c = tid * 4 + j;
        out[(size_t)row * D_MODEL + c] = __float2bfloat16((vv[j] - mu) * rsq * g[c] + b[c]);
    }
}

// ---------------- GEMM v3: A[M,K] bf16 x Bt[N,K] bf16 -> epilogue ----------------
// grid: (M/BM, N/BN)  [M on x so A-tile sharers land on the same XCD]
// BK=64, XOR-8 column swizzle in LDS: full-line staging, 2-way-max fragment reads.
// MODE 0: fused QKV: N=3072; +bias; q *scale -> [B,H,S,Dh]; k -> [B,H,S,Dh];
//         v -> vtout [B,H,Dh,S] (transposed, packed 8B stores)
// MODE 1: +bias +resid(fp32), write bf16 [M,N]
// MODE 2: +bias, fast GELU, write bf16 [M,N]
// MODE 3: +bias +resid(bf16), write fp32 [M,N]
#define BM 128
#define BN 128
#define BK 64

template <int MODE>
__global__ void gemm_kernel(const __hip_bfloat16* __restrict__ A,
                            const __hip_bfloat16* __restrict__ Bt,
                            const float* __restrict__ bias,
                            const void* __restrict__ resid,
                            void* __restrict__ outp, __hip_bfloat16* __restrict__ vtout,
                            int M, int N, int K, float scale) {
    __shared__ __hip_bfloat16 As[BM * BK];  // 16 KB, row stride 128B, groups XOR-swizzled
    __shared__ __hip_bfloat16 Bs[BN * BK];  // 16 KB
    const int tid = threadIdx.x;
    const int lane = tid & 63;
    const int w = tid >> 6;
    const int wm = w >> 1, wn = w & 1;  // 2x2 waves over 128x128
    const int m0 = blockIdx.x * BM;
    const int n0 = blockIdx.y * BN;

    const int srow = lane >> 3;          // 0..7
    const int lgrp = (lane & 7) ^ srow;  // swizzled logical group

    // wave w stages rows [w*32, w*32+32): 4 instrs of 8 rows x 128B each
    const size_t a_base = (size_t)(m0 + w * 32 + srow) * K + lgrp * 8;
    const size_t b_base = (size_t)(n0 + w * 32 + srow) * K + lgrp * 8;

    const floatx4 vzero = {0.f, 0.f, 0.f, 0.f};
    floatx4 acc[4][4];
#pragma unroll
    for (int i = 0; i < 4; ++i)
#pragma unroll
        for (int j = 0; j < 4; ++j) acc[i][j] = vzero;

    const int lcol = lane & 15;
    const int quad = lane >> 4;
    const int arow = wm * 64 + lcol;  // + mt*16
    const int brow = wn * 64 + lcol;  // + nt*16
    const int l7 = lcol & 7;

    for (int kt = 0; kt < K; kt += BK) {
        __syncthreads();
#pragma unroll
        for (int j = 0; j < 4; ++j)
            async_ld16(A + a_base + kt + (size_t)(j * 8) * K, &As[(w * 32 + j * 8) * BK]);
#pragma unroll
        for (int j = 0; j < 4; ++j)
            async_ld16(Bt + b_base + kt + (size_t)(j * 8) * K, &Bs[(w * 32 + j * 8) * BK]);
        __syncthreads();
#pragma unroll
        for (int ks = 0; ks < 2; ++ks) {
            const int g = ((ks * 4 + quad) ^ l7) * 8;
            short8 af[4], bf[4];
#pragma unroll
            for (int mt = 0; mt < 4; ++mt) af[mt] = *(const short8*)&As[(arow + mt * 16) * BK + g];
#pragma unroll
            for (int nt = 0; nt < 4; ++nt) bf[nt] = *(const short8*)&Bs[(brow + nt * 16) * BK + g];
#pragma unroll
            for (int mt = 0; mt < 4; ++mt)
#pragma unroll
                for (int nt = 0; nt < 4; ++nt)
                    acc[mt][nt] = __builtin_amdgcn_mfma_f32_16x16x32_bf16(af[mt], bf[nt], acc[mt][nt], 0, 0, 0);
        }
    }

    const int lrow4 = quad * 4;
#pragma unroll
    for (int mt = 0; mt < 4; ++mt) {
#pragma unroll
        for (int nt = 0; nt < 4; ++nt) {
            const int gm0 = m0 + wm * 64 + mt * 16 + lrow4;
            const int gn = n0 + wn * 64 + nt * 16 + lcol;
            const float bb_ = bias[gn];
            if (MODE == 0) {
                const int which = gn >> 10;  // 0=q 1=k 2=v
                const int rest = gn & 1023;
                const int bb = gm0 >> 11, s = gm0 & (SEQ - 1);
                const int h = rest >> 6, dh = rest & (HEAD_DIM - 1);
                if (which == 2) {
                    short4v pk;
#pragma unroll
                    for (int r = 0; r < 4; ++r) pk[r] = bf16s(acc[mt][nt][r] + bb_);
                    *(short4v*)(vtout + ((size_t)((bb * N_HEADS + h) * HEAD_DIM + dh)) * SEQ + s) = pk;
                } else {
                    const float sc = (which == 0) ? scale : 1.0f;
#pragma unroll
                    for (int r = 0; r < 4; ++r) {
                        float v = (acc[mt][nt][r] + bb_) * sc;
                        ((__hip_bfloat16*)outp)[(size_t)which * NTOK * D_MODEL +
                            ((size_t)(bb * N_HEADS + h) * SEQ + s + r) * HEAD_DIM + dh] =
                            __float2bfloat16(v);
                    }
                }
            } else {
#pragma unroll
                for (int r = 0; r < 4; ++r) {
                    const int gm = gm0 + r;
                    float v = acc[mt][nt][r] + bb_;
                    if (MODE == 1) {  // +resid fp32, write bf16
                        v += ((const float*)resid)[(size_t)gm * N + gn];
                        ((__hip_bfloat16*)outp)[(size_t)gm * N + gn] = __float2bfloat16(v);
                    } else if (MODE == 2) {  // fast GELU, write bf16
                        ((__hip_bfloat16*)outp)[(size_t)gm * N + gn] = __float2bfloat16(fast_gelu(v));
                    } else {  // MODE 3: +resid bf16, write fp32
                        v += __bfloat162float(((const __hip_bfloat16*)resid)[(size_t)gm * N + gn]);
                        ((float*)outp)[(size_t)gm * N + gn] = v;
                    }
                }
            }
        }
    }
}

// ---------------- causal flash attention v5 ----------------
// v4 + single per-wave P buffer (t=0/1 processed sequentially, same-wave DS ordered)
// -> LDS 48KB -> 3 blocks/CU; packed v_cvt_pk_bf16_f32 for the P-pack.
// grid: (8, B*H); block 256. q,k: [B,H,S,Dh] bf16 (q pre-scaled to exp2 domain);
// vt: [B,H,Dh,S] bf16. out: [B,S,D] bf16.
__global__ void __launch_bounds__(256, 3)
attn_kernel(const __hip_bfloat16* __restrict__ q,
            const __hip_bfloat16* __restrict__ k,
            const __hip_bfloat16* __restrict__ vt,
            __hip_bfloat16* __restrict__ o) {
    __shared__ __hip_bfloat16 Ks[2][64 * 64];
    __shared__ __hip_bfloat16 VTs[2][64 * 64];
    __shared__ __hip_bfloat16 Ps[4][32 * 64];  // per-wave P, XOR-8 swizzled (reused across t)

    const int tid = threadIdx.x;
    const int lane = tid & 63;
    const int w = tid >> 6;
    const int bh = blockIdx.y;
    const int b = bh >> 4, h = bh & 15;
    const int q0t[2] = {(int)blockIdx.x * 128, (15 - (int)blockIdx.x) * 128};
    const size_t hb = (size_t)bh * SEQ * HEAD_DIM;
    const size_t vhb = (size_t)bh * HEAD_DIM * SEQ;

    const int lcol = lane & 15;
    const int quad = lane >> 4;
    const int l7 = lcol & 7;
    const int lrow4 = quad * 4;
    const int srow = lane >> 3;           // 0..7
    const int lgrp = (lane & 7) ^ srow;   // staging group (XOR-8 swizzle)

    // Q fragments (B-operand: n=qrow=lcol within 16-slice, k=dh=quad*8+j+32*ks)
    short8 aq[2][2][2];  // [tile][rb][ks]
#pragma unroll
    for (int t = 0; t < 2; ++t)
#pragma unroll
        for (int rb = 0; rb < 2; ++rb)
#pragma unroll
            for (int ks = 0; ks < 2; ++ks)
                aq[t][rb][ks] = *(const short8*)(q + hb +
                    (size_t)(q0t[t] + w * 32 + rb * 16 + lcol) * 64 + ks * 32 + quad * 8);

    const floatx4 vzero = {0.f, 0.f, 0.f, 0.f};
    floatx4 ao[2][2][4];  // [tile][rb][ntv] O accumulator
    floatx4 aol[2][2];    // [tile][rb] row-sum (ones-column trick)
#pragma unroll
    for (int t = 0; t < 2; ++t)
#pragma unroll
        for (int rb = 0; rb < 2; ++rb) {
            aol[t][rb] = vzero;
#pragma unroll
            for (int nt = 0; nt < 4; ++nt) ao[t][rb][nt] = vzero;
        }
    short8 vone;
#pragma unroll
    for (int j = 0; j < 8; ++j) vone[j] = (short)0x3F80;  // bf16 1.0

    const int rounds = 16 - blockIdx.x;  // tile B bound (the larger)

    for (int rd = 0; rd < rounds; ++rd) {
        const int kv0 = rd * 128;
        __syncthreads();
        // stage two 64-key subtiles of K and VT (wave w: 16 rows each)
#pragma unroll
        for (int sub = 0; sub < 2; ++sub)
#pragma unroll
            for (int j = 0; j < 2; ++j) {
                const int rr = w * 16 + j * 8 + srow;
                async_ld16(k + hb + (size_t)(kv0 + sub * 64 + rr) * 64 + lgrp * 8,
                           &Ks[sub][(w * 16 + j * 8) * 64]);
                async_ld16(vt + vhb + (size_t)rr * SEQ + kv0 + sub * 64 + lgrp * 8,
                           &VTs[sub][(w * 16 + j * 8) * 64]);
            }
        __syncthreads();

#pragma unroll
        for (int sub = 0; sub < 2; ++sub) {
            const int kvb = kv0 + sub * 64;
#pragma unroll
            for (int t = 0; t < 2; ++t) {
                const int qw0 = q0t[t] + w * 32;   // wave's first q-row of this tile
                if (kvb > qw0 + 31) continue;      // fully masked

                // ---- S^T = K Q^T (A=K-frag, B=Q-frag) ----
                floatx4 st[2][4];  // [rb][ntk]: row=kcol(quad*4+r), col=qrow(lcol)
#pragma unroll
                for (int rb = 0; rb < 2; ++rb)
#pragma unroll
                    for (int ntk = 0; ntk < 4; ++ntk) st[rb][ntk] = vzero;
#pragma unroll
                for (int ntk = 0; ntk < 4; ++ntk) {
                    const int krow = ntk * 16 + lcol;
                    const short8 ka0 = *(const short8*)&Ks[sub][krow * 64 + ((quad ^ l7) * 8)];
                    const short8 ka1 = *(const short8*)&Ks[sub][krow * 64 + (((4 + quad) ^ l7) * 8)];
#pragma unroll
                    for (int rb = 0; rb < 2; ++rb) {
                        st[rb][ntk] = __builtin_amdgcn_mfma_f32_16x16x32_bf16(ka0, aq[t][rb][0], st[rb][ntk], 0, 0, 0);
                        st[rb][ntk] = __builtin_amdgcn_mfma_f32_16x16x32_bf16(ka1, aq[t][rb][1], st[rb][ntk], 0, 0, 0);
                    }
                }
                // ---- p = exp2(s) (masked->0), packed cvt + b64 write to P ----
                const bool diag = (kvb + 63 > qw0);
#pragma unroll
                for (int rb = 0; rb < 2; ++rb) {
                    const int qrow = qw0 + rb * 16 + lcol;  // this lane's q-row (col idx)
#pragma unroll
                    for (int ntk = 0; ntk < 4; ++ntk) {
                        float p[4];
#pragma unroll
                        for (int r = 0; r < 4; ++r) {
                            const int kcol = kvb + ntk * 16 + lrow4 + r;
                            float e = exp2f(st[rb][ntk][r]);
                            p[r] = (diag && kcol > qrow) ? 0.f : e;
                        }
                        union { short4v s4; unsigned int u[2]; } pk;
                        pk.u[0] = pk_bf16(p[0], p[1]);
                        pk.u[1] = pk_bf16(p[2], p[3]);
                        const int grp = ntk * 2 + (quad >> 1);
                        *(short4v*)&Ps[w][(rb * 16 + lcol) * 64 +
                                         ((grp ^ l7) * 8) + (quad & 1) * 4] = pk.s4;
                    }
                }
                // ---- O += P V ; l += P * ones ----
#pragma unroll
                for (int ks = 0; ks < 2; ++ks) {
                    short8 vbf[4];
#pragma unroll
                    for (int ntv = 0; ntv < 4; ++ntv)
                        vbf[ntv] = *(const short8*)&VTs[sub][(ntv * 16 + lcol) * 64 +
                                                            (((ks * 4 + quad) ^ l7) * 8)];
#pragma unroll
                    for (int rb = 0; rb < 2; ++rb) {
                        const short8 pa = *(const short8*)&Ps[w][(rb * 16 + lcol) * 64 +
                                                                (((ks * 4 + quad) ^ l7) * 8)];
                        aol[t][rb] = __builtin_amdgcn_mfma_f32_16x16x32_bf16(pa, vone, aol[t][rb], 0, 0, 0);
#pragma unroll
                        for (int ntv = 0; ntv < 4; ++ntv)
                            ao[t][rb][ntv] = __builtin_amdgcn_mfma_f32_16x16x32_bf16(pa, vbf[ntv], ao[t][rb][ntv], 0, 0, 0);
                    }
                }
            }
        }
    }
    // epilogue: O / rowsum -> o[b, qrow, h*64+dh]
#pragma unroll
    for (int t = 0; t < 2; ++t)
#pragma unroll
        for (int rb = 0; rb < 2; ++rb)
#pragma unroll
            for (int ntv = 0; ntv < 4; ++ntv)
#pragma unroll
                for (int r = 0; r < 4; ++r) {
                    const int qrow = q0t[t] + w * 32 + rb * 16 + lrow4 + r;
                    const float ov = ao[t][rb][ntv][r] / aol[t][rb][r];
                    o[((size_t)(b * SEQ) + qrow) * D_MODEL + h * HEAD_DIM + ntv * 16 + lcol] =
                        __float2bfloat16(ov);
                }
}

// ---------------- launch ----------------
extern "C" void kernel_launch(void* const* d_in, const int* in_sizes, int n_in,
                              void* d_out, int out_size, void* d_ws, size_t ws_size,
                              hipStream_t stream) {
    (void)in_sizes; (void)n_in; (void)out_size; (void)ws_size;
    const float* x    = (const float*)d_in[0];
    const float* wq   = (const float*)d_in[1];
    const float* bq   = (const float*)d_in[2];
    const float* wk   = (const float*)d_in[3];
    const float* bk   = (const float*)d_in[4];
    const float* wv   = (const float*)d_in[5];
    const float* bv   = (const float*)d_in[6];
    const float* wo   = (const float*)d_in[7];
    const float* bo   = (const float*)d_in[8];
    const float* w1   = (const float*)d_in[9];
    const float* b1   = (const float*)d_in[10];
    const float* w2   = (const float*)d_in[11];
    const float* b2   = (const float*)d_in[12];
    const float* ln1g = (const float*)d_in[13];
    const float* ln1b = (const float*)d_in[14];
    const float* ln2g = (const float*)d_in[15];
    const float* ln2b = (const float*)d_in[16];
    float* out = (float*)d_out;

    char* ws = (char*)d_ws;
    size_t off = 0;
    auto alloc = [&](size_t bytes) { void* p = ws + off; off += bytes; return p; };
    __hip_bfloat16* wqkvT = (__hip_bfloat16*)alloc((size_t)3072 * 1024 * 2);
    __hip_bfloat16* woT = (__hip_bfloat16*)alloc((size_t)1024 * 1024 * 2);
    __hip_bfloat16* w1T = (__hip_bfloat16*)alloc((size_t)4096 * 1024 * 2);
    __hip_bfloat16* w2T = (__hip_bfloat16*)alloc((size_t)4096 * 1024 * 2);
    float* bqkv = (float*)alloc((size_t)3072 * 4);
    __hip_bfloat16* normed = (__hip_bfloat16*)alloc((size_t)NTOK * D_MODEL * 2);  // reused as LN2 out
    __hip_bfloat16* qb = (__hip_bfloat16*)alloc((size_t)NTOK * D_MODEL * 2);
    __hip_bfloat16* kb = (__hip_bfloat16*)alloc((size_t)NTOK * D_MODEL * 2);  // = qb + 16MB (MODE0 which=1)
    __hip_bfloat16* attnb = (__hip_bfloat16*)alloc((size_t)NTOK * D_MODEL * 2);
    __hip_bfloat16* x1 = (__hip_bfloat16*)alloc((size_t)NTOK * D_MODEL * 2);  // bf16 residual
    __hip_bfloat16* hh = (__hip_bfloat16*)alloc((size_t)NTOK * D_FF * 2);
    __hip_bfloat16* vtb = (__hip_bfloat16*)hh;  // vt live only before attn; hh only after -> share

    const float QSCALE = 0.125f * 1.44269504088896f;  // exp2 domain

    const dim3 blk(256);
    prep_kernel<<<dim3(12300), blk, 0, stream>>>(wq, wk, wv, wo, w1, w2, bq, bk, bv,
                                                 wqkvT, woT, w1T, w2T, bqkv);

    ln_kernel<<<NTOK, blk, 0, stream>>>(x, ln1g, ln1b, normed);

    // grid: (M-blocks, N-blocks) -> A-tile sharers on same XCD
    gemm_kernel<0><<<dim3(NTOK / BM, 3072 / BN), blk, 0, stream>>>(normed, wqkvT, bqkv, nullptr, qb, vtb, NTOK, 3072, 1024, QSCALE);

    attn_kernel<<<dim3(8, BATCH * N_HEADS), blk, 0, stream>>>(qb, kb, vtb, attnb);

    gemm_kernel<1><<<dim3(NTOK / BM, 1024 / BN), blk, 0, stream>>>(attnb, woT, bo, x, x1, nullptr, NTOK, 1024, 1024, 1.0f);

    ln_bf16_kernel<<<NTOK, blk, 0, stream>>>(x1, ln2g, ln2b, normed);

    gemm_kernel<2><<<dim3(NTOK / BM, D_FF / BN), blk, 0, stream>>>(normed, w1T, b1, nullptr, hh, nullptr, NTOK, D_FF, 1024, 1.0f);
    gemm_kernel<3><<<dim3(NTOK / BM, 1024 / BN), blk, 0, stream>>>(hh, w2T, b2, x1, out, nullptr, NTOK, 1024, D_FF, 1.0f);
}